// Round 1
// baseline (1087.610 us; speedup 1.0000x reference)
//
#include <hip/hip_runtime.h>

// Problem constants (fixed by the reference)
#define SQ 2048   // sequence length
#define DM 2048   // model dim
#define NH 16     // heads
#define HD 128    // head dim
#define NB 2      // batch
#define NBH 32    // NB*NH

typedef __attribute__((ext_vector_type(8))) short bf16x8;
typedef __attribute__((ext_vector_type(4))) float f32x4;

__device__ __forceinline__ unsigned short f2bf(float f) {
    unsigned u = __float_as_uint(f);
    u += 0x7FFFu + ((u >> 16) & 1u);   // round-to-nearest-even
    return (unsigned short)(u >> 16);
}
__device__ __forceinline__ float bf2f(unsigned short h) {
    return __uint_as_float(((unsigned)h) << 16);
}

// ---------------------------------------------------------------------------
// Prep 1: K fp32 [b][s][h*128+d]  ->  bf16 [bh][s][d]
// ---------------------------------------------------------------------------
__global__ __launch_bounds__(256) void kconv_kernel(const float* __restrict__ src,
                                                    unsigned short* __restrict__ dst) {
    int e4 = blockIdx.x * 256 + threadIdx.x;     // one float4 per thread, 2M total
    int d4 = e4 & 31;
    int s  = (e4 >> 5) & (SQ - 1);
    int bh = e4 >> 16;                           // SQ*HD/4 = 65536 f4 per bh
    int b = bh >> 4, h = bh & 15;
    const float4 v = *(const float4*)(src + ((size_t)(b * SQ + s)) * DM + h * HD + d4 * 4);
    ushort4 o;
    o.x = f2bf(v.x); o.y = f2bf(v.y); o.z = f2bf(v.z); o.w = f2bf(v.w);
    *(ushort4*)(dst + ((size_t)bh * SQ + s) * HD + d4 * 4) = o;
}

// ---------------------------------------------------------------------------
// Prep 2: V fp32 [b][s][h*128+d]  ->  bf16 transposed [bh][d][s]
// LDS-tiled transpose: 64 seq x 128 d per block. Both global sides coalesced.
// ---------------------------------------------------------------------------
__global__ __launch_bounds__(256) void vtrans_kernel(const float* __restrict__ src,
                                                     unsigned short* __restrict__ dst) {
    __shared__ unsigned short tl[128 * 66];      // [d][s] tile, pad 66 vs 64
    int bh = blockIdx.x >> 5;
    int s0 = (blockIdx.x & 31) * 64;
    int b = bh >> 4, h = bh & 15;
    #pragma unroll
    for (int i = 0; i < 8; ++i) {
        int e4 = threadIdx.x + 256 * i;          // 0..2047 float4s
        int d4 = e4 & 31;
        int s  = e4 >> 5;                        // 0..63
        const float4 v = *(const float4*)(src + ((size_t)(b * SQ + s0 + s)) * DM + h * HD + d4 * 4);
        tl[(d4 * 4 + 0) * 66 + s] = f2bf(v.x);
        tl[(d4 * 4 + 1) * 66 + s] = f2bf(v.y);
        tl[(d4 * 4 + 2) * 66 + s] = f2bf(v.z);
        tl[(d4 * 4 + 3) * 66 + s] = f2bf(v.w);
    }
    __syncthreads();
    #pragma unroll
    for (int i = 0; i < 16; ++i) {
        int o  = threadIdx.x + 256 * i;          // 128 rows x 32 uints
        int d  = o >> 5;
        int s2 = o & 31;
        unsigned u = *(const unsigned*)(tl + d * 66 + s2 * 2);
        *(unsigned*)(dst + ((size_t)(bh * HD + d)) * SQ + s0 + s2 * 2) = u;
    }
}

// ---------------------------------------------------------------------------
// Main fused attention kernel.
// Block = (bh, 16-row Q tile), 256 threads = 4 waves.
//   Phase 1: Q tile -> LDS bf16
//   Phase 2: scores = scale*Q K^T + mask -> LDS bf16 (full 16 x 2048 rows)
//   Phase 3: row max, exp (stored back in place), row sum
//   Phase 4: normalize; write fp32 weights to global; bf16 weights in LDS
//   Phase 5: O = W @ V via MFMA with V^T bf16 from ws
// ---------------------------------------------------------------------------
#define WSTRIDE 2056   // 2048 + 8 pad; *2B = 4112 B = 257*16 (16B-aligned rows, 4-bank skew)

__global__ __launch_bounds__(256) void attn_kernel(
    const float* __restrict__ q, const float* __restrict__ mask,
    const unsigned short* __restrict__ kbf, const unsigned short* __restrict__ vt,
    float* __restrict__ outO, float* __restrict__ outW) {

    __shared__ __align__(16) unsigned short q_lds[16 * 136];
    __shared__ __align__(16) unsigned short w_lds[16 * WSTRIDE];
    __shared__ float red[2][16][17];
    __shared__ float rlrow[16];

    const int tid = threadIdx.x;
    const int bh = blockIdx.x >> 7;              // 128 q-tiles per bh
    const int q0 = (blockIdx.x & 127) << 4;
    const int b = bh >> 4, h = bh & 15;

    // ---- Phase 1: Q tile (16 x 128) -> LDS bf16 ----
    #pragma unroll
    for (int i = 0; i < 2; ++i) {
        int e4 = tid + 256 * i;                  // 512 float4s
        int row = e4 >> 5, c4 = e4 & 31;
        const float4 v = *(const float4*)(q + ((size_t)(b * SQ + q0 + row)) * DM + h * HD + c4 * 4);
        ushort4 o; o.x = f2bf(v.x); o.y = f2bf(v.y); o.z = f2bf(v.z); o.w = f2bf(v.w);
        *(ushort4*)(q_lds + row * 136 + c4 * 4) = o;
    }
    __syncthreads();

    const int wave = tid >> 6, lane = tid & 63, quad = lane >> 4, ln = lane & 15;
    const float scale = 0.08838834764831845f;    // 1/sqrt(128)

    // A-fragments (Q) are invariant across score column tiles: cache all 4 k-steps.
    bf16x8 afr[4];
    #pragma unroll
    for (int ks = 0; ks < 4; ++ks)
        afr[ks] = *(const bf16x8*)(q_lds + ln * 136 + ks * 32 + quad * 8);

    // ---- Phase 2: QK^T, each wave handles a 16-col stripe per iteration ----
    const unsigned short* kb = kbf + (size_t)bh * (SQ * HD);
    const float* mb = mask + b * SQ;
    for (int it = 0; it < 32; ++it) {
        int n0 = it * 64 + wave * 16;
        f32x4 acc = {0.f, 0.f, 0.f, 0.f};
        const unsigned short* kr = kb + (size_t)(n0 + ln) * HD + quad * 8;
        #pragma unroll
        for (int ks = 0; ks < 4; ++ks) {
            bf16x8 bfr = *(const bf16x8*)(kr + ks * 32);
            acc = __builtin_amdgcn_mfma_f32_16x16x32_bf16(afr[ks], bfr, acc, 0, 0, 0);
        }
        float mv = mb[n0 + ln];
        #pragma unroll
        for (int r = 0; r < 4; ++r)   // C layout: row = quad*4+reg, col = ln
            w_lds[(quad * 4 + r) * WSTRIDE + n0 + ln] = f2bf(acc[r] * scale + mv);
    }
    __syncthreads();

    // ---- Phase 3: softmax stats (thread t: row t>>4, 128-col chunk t&15) ----
    {
        int r = tid >> 4, c = tid & 15;
        unsigned short* base = w_lds + r * WSTRIDE + c * 128;
        float lm = -3.4e38f;
        for (int i = 0; i < 32; ++i) {
            ushort4 u = *(ushort4*)(base + i * 4);
            lm = fmaxf(lm, fmaxf(fmaxf(bf2f(u.x), bf2f(u.y)), fmaxf(bf2f(u.z), bf2f(u.w))));
        }
        red[0][r][c] = lm;
        __syncthreads();
        float m = red[0][r][0];
        #pragma unroll
        for (int j = 1; j < 16; ++j) m = fmaxf(m, red[0][r][j]);
        float ls = 0.f;
        for (int i = 0; i < 32; ++i) {           // exp once; store back in place
            ushort4 u = *(ushort4*)(base + i * 4);
            float e0 = __expf(bf2f(u.x) - m);
            float e1 = __expf(bf2f(u.y) - m);
            float e2 = __expf(bf2f(u.z) - m);
            float e3 = __expf(bf2f(u.w) - m);
            ls += (e0 + e1) + (e2 + e3);
            u.x = f2bf(e0); u.y = f2bf(e1); u.z = f2bf(e2); u.w = f2bf(e3);
            *(ushort4*)(base + i * 4) = u;
        }
        red[1][r][c] = ls;
        __syncthreads();
        if (c == 0) {
            float l = 0.f;
            #pragma unroll
            for (int j = 0; j < 16; ++j) l += red[1][r][j];
            rlrow[r] = 1.0f / l;
        }
    }
    __syncthreads();

    // ---- Phase 4: normalize, coalesced fp32 weight store, bf16 back to LDS ----
    float* wbase = outW + ((size_t)bh * SQ + q0) * SQ;
    for (int i = 0; i < 32; ++i) {
        int e4 = tid + 256 * i;                  // 8192 float4s over 16 x 2048
        int rr = e4 >> 9;
        int c4 = (e4 & 511) * 4;
        float rl = rlrow[rr];
        unsigned short* p = w_lds + rr * WSTRIDE + c4;
        ushort4 u = *(ushort4*)p;
        float4 w;
        w.x = bf2f(u.x) * rl; w.y = bf2f(u.y) * rl;
        w.z = bf2f(u.z) * rl; w.w = bf2f(u.w) * rl;
        *(float4*)(wbase + (size_t)rr * SQ + c4) = w;
        u.x = f2bf(w.x); u.y = f2bf(w.y); u.z = f2bf(w.z); u.w = f2bf(w.w);
        *(ushort4*)p = u;
    }
    __syncthreads();

    // ---- Phase 5: O = W @ V.  Wave handles 32 output cols (2 n-tiles). ----
    {
        int d0 = wave * 32;
        f32x4 o0 = {0.f, 0.f, 0.f, 0.f}, o1 = {0.f, 0.f, 0.f, 0.f};
        const unsigned short* vb  = vt + (size_t)bh * (HD * SQ);
        const unsigned short* v0p = vb + (size_t)(d0 + ln) * SQ + quad * 8;
        const unsigned short* v1p = v0p + (size_t)16 * SQ;
        const unsigned short* ap  = w_lds + ln * WSTRIDE + quad * 8;
        for (int kk = 0; kk < 64; ++kk) {
            bf16x8 a  = *(const bf16x8*)(ap + kk * 32);
            bf16x8 b0 = *(const bf16x8*)(v0p + kk * 32);
            bf16x8 b1 = *(const bf16x8*)(v1p + kk * 32);
            o0 = __builtin_amdgcn_mfma_f32_16x16x32_bf16(a, b0, o0, 0, 0, 0);
            o1 = __builtin_amdgcn_mfma_f32_16x16x32_bf16(a, b1, o1, 0, 0, 0);
        }
        float* ob = outO + ((size_t)(b * SQ + q0)) * DM + h * HD;
        #pragma unroll
        for (int r = 0; r < 4; ++r) {
            int row = quad * 4 + r;
            ob[(size_t)row * DM + d0 + ln]      = o0[r];
            ob[(size_t)row * DM + d0 + 16 + ln] = o1[r];
        }
    }
}

// ---------------------------------------------------------------------------
extern "C" void kernel_launch(void* const* d_in, const int* in_sizes, int n_in,
                              void* d_out, int out_size, void* d_ws, size_t ws_size,
                              hipStream_t stream) {
    const float* q    = (const float*)d_in[0];
    const float* k    = (const float*)d_in[1];
    const float* v    = (const float*)d_in[2];
    const float* mask = (const float*)d_in[3];

    float* outO = (float*)d_out;
    float* outW = outO + (size_t)NB * SQ * DM;   // attn_weights after attn_output

    const size_t elems = (size_t)NBH * SQ * HD;  // 8,388,608 per tensor
    if (ws_size < 2 * elems * sizeof(unsigned short)) return;  // need 33.5 MB scratch
    unsigned short* kbf = (unsigned short*)d_ws;
    unsigned short* vtp = kbf + elems;

    kconv_kernel<<<8192, 256, 0, stream>>>(k, kbf);
    vtrans_kernel<<<1024, 256, 0, stream>>>(v, vtp);
    attn_kernel<<<4096, 256, 0, stream>>>(q, mask, kbf, vtp, outO, outW);
}